// Round 1
// 223.361 us; speedup vs baseline: 1.0873x; 1.0873x over previous
//
#include <hip/hip_runtime.h>
#include <hip/hip_bf16.h>
#include <math.h>

typedef unsigned short u16;

#define BATCH 16384
#define HID   512
#define KDIM  1024   // INPUT + HIDDEN
#define BM    128    // batch rows per block
#define NSTEP 16     // K-steps of 64

typedef __bf16 bf16x8 __attribute__((ext_vector_type(8)));
typedef float  floatx4 __attribute__((ext_vector_type(4)));

__device__ __forceinline__ float fast_sigmoid(float x) {
  return 1.0f / (1.0f + __expf(-x));
}
__device__ __forceinline__ float fast_tanh(float x) {
  float e = __expf(-2.0f * fabsf(x));
  float t = (1.0f - e) / (1.0f + e);
  return x >= 0.0f ? t : -t;
}
__device__ __forceinline__ u16 f2bf(float f) {
  return __builtin_bit_cast(u16, __float2bfloat16(f));
}

// ---------- pre-pass: W only (X pack fused into the GEMM this round) ----------
// Wf: MFMA-FRAGMENT-MAJOR weights so B-loads are one coalesced dwordx4:
//   elem (gate g, per-gate col n, k) lives at
//   (((g*32 + n/16)*32 + k/32)*64 + ((k>>3)&3)*16 + (n&15))*8 + (k&7)
//   -> [tile128][kstep32][lane64][8elems]; verified B-fragment layout (R1-R3
//   of the previous session).
__global__ __launch_bounds__(256) void pack_w_kernel(
    const float* __restrict__ Wi, const float* __restrict__ Wf_,
    const float* __restrict__ Wo, const float* __restrict__ Wg,
    u16* __restrict__ Wf) {
  int grow = blockIdx.x;                  // 0..2047, order [Wi|Wf|Wo|Wg]
  int k = threadIdx.x * 4;
  int g = grow >> 9;
  int n = grow & (HID - 1);
  const float* s = g == 0 ? Wi : g == 1 ? Wf_ : g == 2 ? Wo : Wg;
  float4 v = *(const float4*)(s + (size_t)n * KDIM + k);
  ushort4 o;
  o.x = f2bf(v.x); o.y = f2bf(v.y); o.z = f2bf(v.z); o.w = f2bf(v.w);
  size_t d = ((size_t)((g * 32 + (n >> 4)) * 32 + (k >> 5)) * 64 +
              ((k >> 3) & 3) * 16 + (n & 15)) * 8 + (k & 7);
  *(ushort4*)(Wf + d) = o;   // k%8 in {0,4} -> 8B-aligned
}

// ---------- main fused GEMM + LSTM epilogue ----------
// This round: X is staged fp32->bf16 IN-KERNEL (reg-staged, T14 split):
//   * global fp32 loads for step S+1 issued BEFORE compute(S)
//   * cvt + swizzled ds_write_b128 AFTER compute(S), before the barrier
// LDS layout/swizzle identical to the verified global_load_lds version:
//   LDS[row][c*8+e] = X[row][S*64 + (c^(row&7))*8 + e], rows 0..127, 64 elems.
// B: single register buffer (frees 32 VGPRs to pay for the prefetch regs —
// we sit at the 256-unified-regs/wave occupancy cliff); loadB(S+1) issued
// right after compute(S)'s last use of b, latency hidden under cvt/barrier.
__global__ __launch_bounds__(512, 2) void lstm_gemm_kernel(
    const float* __restrict__ input_, const float* __restrict__ prev_h,
    const u16* __restrict__ Wf,
    const float* __restrict__ Bi, const float* __restrict__ Bf,
    const float* __restrict__ Bo, const float* __restrict__ Bg,
    const float* __restrict__ prevC, float* __restrict__ out) {
  __shared__ u16 lds[2][8192];   // per buf: 128 rows x 64 elems = 16 KB

  const int tid = threadIdx.x;
  const int wave = tid >> 6, lane = tid & 63;
  const int lrow = lane & 15, lquad = lane >> 4;
  const int m_block = blockIdx.x * BM;
  const int ntg = blockIdx.y * 8 + wave;   // global per-gate 16-col tile id

  // Staging geometry: wave covers rows [wave*16, wave*16+16); instr i covers
  // rows li*8+(lane>>3), li = wave*2+i. Lane fetches the swizzled 8-elem
  // chunk (lane&7)^(row&7) of its row, 8 fp32 = 2 float4 per step.
  const int swzf = ((lane & 7) ^ ((lane >> 3) & 7)) * 8;  // in elements
  const float* xh[2];   // prev_h row base (+swizzle), K-steps 0..7
  const float* xi[2];   // input_ row base (+swizzle), K-steps 8..15
  int lp[2];            // LDS elem offset this lane writes
#pragma unroll
  for (int i = 0; i < 2; ++i) {
    int li = wave * 2 + i;
    int row = m_block + li * 8 + (lane >> 3);
    xh[i] = prev_h + (size_t)row * HID + swzf;
    xi[i] = input_ + (size_t)row * HID + swzf;
    lp[i] = li * 512 + lane * 8;
  }

  floatx4 acc[4][8];   // [gate][m-tile]  (AGPRs)
#pragma unroll
  for (int g = 0; g < 4; ++g)
#pragma unroll
    for (int mt = 0; mt < 8; ++mt)
      acc[g][mt] = (floatx4){0.f, 0.f, 0.f, 0.f};

  float4 r[2][2];      // in-flight fp32 X for next step (16 VGPRs)
  auto ldX = [&](int S) {
#pragma unroll
    for (int i = 0; i < 2; ++i) {
      const float* base = (S < 8) ? (xh[i] + S * 64) : (xi[i] + (S - 8) * 64);
      r[i][0] = *(const float4*)(base);
      r[i][1] = *(const float4*)(base + 4);
    }
  };

  auto cvtWrite = [&](int buf) {
#pragma unroll
    for (int i = 0; i < 2; ++i) {
      union { u16 u[8]; bf16x8 v; } t;
      t.u[0] = f2bf(r[i][0].x); t.u[1] = f2bf(r[i][0].y);
      t.u[2] = f2bf(r[i][0].z); t.u[3] = f2bf(r[i][0].w);
      t.u[4] = f2bf(r[i][1].x); t.u[5] = f2bf(r[i][1].y);
      t.u[6] = f2bf(r[i][1].z); t.u[7] = f2bf(r[i][1].w);
      *(bf16x8*)(&lds[buf][lp[i]]) = t.v;   // 16B-aligned, conflict-free
    }
  };

  bf16x8 b[2][4];      // single B buffer (32 VGPRs)
  auto loadB = [&](int S) {
#pragma unroll
    for (int kk = 0; kk < 2; ++kk)
#pragma unroll
      for (int g = 0; g < 4; ++g)
        b[kk][g] = *(const bf16x8*)(
            Wf + (((size_t)(g * 32 + ntg) * 32 + (S * 2 + kk)) << 9) +
            lane * 8);
  };

  auto compute = [&](int buf) {
    const u16* LA = &lds[buf][0];
#pragma unroll
    for (int kk = 0; kk < 2; ++kk) {
#pragma unroll
      for (int mt = 0; mt < 8; ++mt) {
        bf16x8 a = *(const bf16x8*)
            &LA[(mt * 16 + lrow) * 64 + (((kk * 4 + lquad) ^ (lrow & 7)) * 8)];
#pragma unroll
        for (int g = 0; g < 4; ++g)
          acc[g][mt] = __builtin_amdgcn_mfma_f32_16x16x32_bf16(
              a, b[kk][g], acc[g][mt], 0, 0, 0);
      }
    }
  };

  // prologue
  loadB(0);
  ldX(0);
  cvtWrite(0);
  __syncthreads();

  // One barrier per K-step. Buffer hazard check: in iter S every wave reads
  // buf=S&1 and writes buf^1; buf^1 was last read in iter S-1, completed
  // before the iter-S-1 barrier.
  for (int S = 0; S < NSTEP; ++S) {
    const int buf = S & 1;
    if (S + 1 < NSTEP) ldX(S + 1);     // issue early; waited on in cvtWrite
    compute(buf);
    if (S + 1 < NSTEP) {
      loadB(S + 1);                    // issues after b's last use (WAR ok)
      cvtWrite(buf ^ 1);               // vmcnt waits only on ldX's 4 loads
    }
    __syncthreads();
  }

  // Epilogue. C layout (verified): col=lane&15, row=lquad*4+reg.
  const int j = ntg * 16 + lrow;        // 0..511
  const float vbi = Bi[j], vbf = Bf[j], vbo = Bo[j], vbg = Bg[j];
  float* outH = out;
  float* outC = out + (size_t)BATCH * HID;
#pragma unroll
  for (int mt = 0; mt < 8; ++mt) {
    int rowb = m_block + mt * 16 + lquad * 4;
#pragma unroll
    for (int rg = 0; rg < 4; ++rg) {
      int row = rowb + rg;
      float gi = fast_sigmoid(acc[0][mt][rg] + vbi);
      float gf = fast_sigmoid(acc[1][mt][rg] + vbf);
      float go = fast_sigmoid(acc[2][mt][rg] + vbo);
      float gg = fast_tanh(acc[3][mt][rg] + vbg);
      float c = gf * prevC[row * HID + j] + gi * gg;
      float h = fast_tanh(c) * go;
      outH[row * HID + j] = h;
      outC[row * HID + j] = c;
    }
  }
}

// ---------- slow fallback if ws too small (correctness insurance) ----------
__global__ void lstm_fallback_kernel(
    const float* __restrict__ input_, const float* __restrict__ prev_h,
    const float* __restrict__ prevC,
    const float* __restrict__ Wi, const float* __restrict__ Bi,
    const float* __restrict__ Wf, const float* __restrict__ Bf,
    const float* __restrict__ Wo, const float* __restrict__ Bo,
    const float* __restrict__ Wg, const float* __restrict__ Bg,
    float* __restrict__ out) {
  int idx = blockIdx.x * blockDim.x + threadIdx.x;
  int b = idx / HID, j = idx % HID;
  if (b >= BATCH) return;
  float si = 0.f, sf = 0.f, so = 0.f, sg = 0.f;
  for (int k = 0; k < KDIM; ++k) {
    float x = (k < HID) ? prev_h[b * HID + k] : input_[b * HID + (k - HID)];
    si += x * Wi[j * KDIM + k];
    sf += x * Wf[j * KDIM + k];
    so += x * Wo[j * KDIM + k];
    sg += x * Wg[j * KDIM + k];
  }
  float gi = fast_sigmoid(si + Bi[j]);
  float gf = fast_sigmoid(sf + Bf[j]);
  float go = fast_sigmoid(so + Bo[j]);
  float gg = fast_tanh(sg + Bg[j]);
  float c = gf * prevC[b * HID + j] + gi * gg;
  out[b * HID + j] = fast_tanh(c) * go;
  out[(size_t)BATCH * HID + b * HID + j] = c;
}

extern "C" void kernel_launch(void* const* d_in, const int* in_sizes, int n_in,
                              void* d_out, int out_size, void* d_ws, size_t ws_size,
                              hipStream_t stream) {
  const float* input_ = (const float*)d_in[0];
  const float* prev_h = (const float*)d_in[1];
  const float* prev_c = (const float*)d_in[2];
  const float* W_i = (const float*)d_in[3];
  const float* b_i = (const float*)d_in[4];
  const float* W_f = (const float*)d_in[5];
  const float* b_f = (const float*)d_in[6];
  const float* W_g = (const float*)d_in[7];
  const float* b_g = (const float*)d_in[8];
  const float* W_o = (const float*)d_in[9];
  const float* b_o = (const float*)d_in[10];
  float* out = (float*)d_out;

  const size_t ws_needed = (size_t)4 * HID * KDIM * sizeof(u16);   // 4 MB

  if (ws_size < ws_needed) {
    int total = BATCH * HID;
    lstm_fallback_kernel<<<(total + 255) / 256, 256, 0, stream>>>(
        input_, prev_h, prev_c, W_i, b_i, W_f, b_f, W_o, b_o, W_g, b_g, out);
    return;
  }

  u16* Wfp = (u16*)d_ws;                      // fragment-major bf16 W, 4 MB

  pack_w_kernel<<<4 * HID, 256, 0, stream>>>(W_i, W_f, W_o, W_g, Wfp);

  dim3 grid(BATCH / BM, HID / 128);           // 128 x 4 = 512 blocks
  lstm_gemm_kernel<<<grid, 512, 0, stream>>>(input_, prev_h, Wfp,
                                             b_i, b_f, b_o, b_g, prev_c, out);
}